// Round 1
// baseline (113.742 us; speedup 1.0000x reference)
//
#include <hip/hip_runtime.h>
#include <float.h>
#include <math.h>

// B=65536 rows, C=1000 cols, fp32.
// Kernel 1: one wave (64 lanes) per row. Row cached in 16 VGPRs (4x float4/lane).
//   pass1: max, then S=sum exp(x-m), W=sum exp(x-m)*x, L=dot(x,wL), x_label
//   T = clip(softplus(L + wH*(H_hat/ln C) + b), EPS)
//   pass2 (registers): S2 = sum exp((x-m)/T); nll = log(S2) + (m - x_label)/T
// Kernel 2: deterministic mean over B in double precision (sum ~6e11, terms up
//   to ~1e7 -> fp32 naive accumulation would lose too much).

static constexpr int kC4    = 250;   // float4 per row (1000 floats)
static constexpr int kBlock = 256;   // 4 waves per block, 1 wave per row
static constexpr float kEps = 1.1920928955078125e-07f;  // FLT_EPSILON
static constexpr float kLogC = 6.907755279f;            // ln(1000)

__device__ __forceinline__ float wred_max(float v) {
#pragma unroll
  for (int off = 32; off > 0; off >>= 1) v = fmaxf(v, __shfl_xor(v, off, 64));
  return v;
}
__device__ __forceinline__ float wred_sum(float v) {
#pragma unroll
  for (int off = 32; off > 0; off >>= 1) v += __shfl_xor(v, off, 64);
  return v;
}

__global__ __launch_bounds__(kBlock) void ats_row_kernel(
    const float* __restrict__ X, const int* __restrict__ labels,
    const float* __restrict__ wL, const float* __restrict__ wH,
    const float* __restrict__ bb, float* __restrict__ nll_out, int B) {
  const int lane = threadIdx.x & 63;
  const int row  = (int)((blockIdx.x * (unsigned)kBlock + threadIdx.x) >> 6);
  if (row >= B) return;

  const float4* Xr  = reinterpret_cast<const float4*>(X) + (size_t)row * kC4;
  const float4* WLr = reinterpret_cast<const float4*>(wL);

  float L = 0.f, m = -FLT_MAX;
  float4 x0, x1, x2, x3;
  {
    float4 w;
    x0 = Xr[lane];        w = WLr[lane];
    L = fmaf(x0.x, w.x, L); L = fmaf(x0.y, w.y, L); L = fmaf(x0.z, w.z, L); L = fmaf(x0.w, w.w, L);
    m = fmaxf(m, fmaxf(fmaxf(x0.x, x0.y), fmaxf(x0.z, x0.w)));
    x1 = Xr[64 + lane];   w = WLr[64 + lane];
    L = fmaf(x1.x, w.x, L); L = fmaf(x1.y, w.y, L); L = fmaf(x1.z, w.z, L); L = fmaf(x1.w, w.w, L);
    m = fmaxf(m, fmaxf(fmaxf(x1.x, x1.y), fmaxf(x1.z, x1.w)));
    x2 = Xr[128 + lane];  w = WLr[128 + lane];
    L = fmaf(x2.x, w.x, L); L = fmaf(x2.y, w.y, L); L = fmaf(x2.z, w.z, L); L = fmaf(x2.w, w.w, L);
    m = fmaxf(m, fmaxf(fmaxf(x2.x, x2.y), fmaxf(x2.z, x2.w)));
    if (lane < kC4 - 192) {  // lanes 0..57 hold the tail
      x3 = Xr[192 + lane];  w = WLr[192 + lane];
      L = fmaf(x3.x, w.x, L); L = fmaf(x3.y, w.y, L); L = fmaf(x3.z, w.z, L); L = fmaf(x3.w, w.w, L);
      m = fmaxf(m, fmaxf(fmaxf(x3.x, x3.y), fmaxf(x3.z, x3.w)));
    } else {
      x3 = make_float4(-FLT_MAX, -FLT_MAX, -FLT_MAX, -FLT_MAX);  // finite sentinel
    }
  }
  m = wred_max(m);

  const int lab = labels[row];
  float S = 0.f, W = 0.f, xl = 0.f;
  {
    float e;
    // slot 0, element base lane*4
    e = __expf(x0.x - m); S += e; W = fmaf(e, x0.x, W); if (lane * 4 + 0 == lab) xl = x0.x;
    e = __expf(x0.y - m); S += e; W = fmaf(e, x0.y, W); if (lane * 4 + 1 == lab) xl = x0.y;
    e = __expf(x0.z - m); S += e; W = fmaf(e, x0.z, W); if (lane * 4 + 2 == lab) xl = x0.z;
    e = __expf(x0.w - m); S += e; W = fmaf(e, x0.w, W); if (lane * 4 + 3 == lab) xl = x0.w;
    const int b1 = (64 + lane) * 4;
    e = __expf(x1.x - m); S += e; W = fmaf(e, x1.x, W); if (b1 + 0 == lab) xl = x1.x;
    e = __expf(x1.y - m); S += e; W = fmaf(e, x1.y, W); if (b1 + 1 == lab) xl = x1.y;
    e = __expf(x1.z - m); S += e; W = fmaf(e, x1.z, W); if (b1 + 2 == lab) xl = x1.z;
    e = __expf(x1.w - m); S += e; W = fmaf(e, x1.w, W); if (b1 + 3 == lab) xl = x1.w;
    const int b2 = (128 + lane) * 4;
    e = __expf(x2.x - m); S += e; W = fmaf(e, x2.x, W); if (b2 + 0 == lab) xl = x2.x;
    e = __expf(x2.y - m); S += e; W = fmaf(e, x2.y, W); if (b2 + 1 == lab) xl = x2.y;
    e = __expf(x2.z - m); S += e; W = fmaf(e, x2.z, W); if (b2 + 2 == lab) xl = x2.z;
    e = __expf(x2.w - m); S += e; W = fmaf(e, x2.w, W); if (b2 + 3 == lab) xl = x2.w;
    const int b3 = (192 + lane) * 4;  // >= 1000 for invalid lanes -> never == lab
    e = __expf(x3.x - m); S += e; W = fmaf(e, x3.x, W); if (b3 + 0 == lab) xl = x3.x;
    e = __expf(x3.y - m); S += e; W = fmaf(e, x3.y, W); if (b3 + 1 == lab) xl = x3.y;
    e = __expf(x3.z - m); S += e; W = fmaf(e, x3.z, W); if (b3 + 2 == lab) xl = x3.z;
    e = __expf(x3.w - m); S += e; W = fmaf(e, x3.w, W); if (b3 + 3 == lab) xl = x3.w;
  }
  S  = wred_sum(S);
  W  = wred_sum(W);
  L  = wred_sum(L);
  xl = wred_sum(xl);

  const float Hhat = W / S - m - __logf(S);
  const float HTS  = wH[0] * (Hhat / kLogC) + bb[0];
  const float a    = L + HTS;
  const float sp   = (a > 0.f) ? (a + log1pf(__expf(-a))) : log1pf(__expf(a));
  const float T    = fmaxf(sp, kEps);
  const float rT   = 1.0f / T;

  float S2 = 0.f;
  S2 += __expf((x0.x - m) * rT); S2 += __expf((x0.y - m) * rT);
  S2 += __expf((x0.z - m) * rT); S2 += __expf((x0.w - m) * rT);
  S2 += __expf((x1.x - m) * rT); S2 += __expf((x1.y - m) * rT);
  S2 += __expf((x1.z - m) * rT); S2 += __expf((x1.w - m) * rT);
  S2 += __expf((x2.x - m) * rT); S2 += __expf((x2.y - m) * rT);
  S2 += __expf((x2.z - m) * rT); S2 += __expf((x2.w - m) * rT);
  S2 += __expf((x3.x - m) * rT); S2 += __expf((x3.y - m) * rT);
  S2 += __expf((x3.z - m) * rT); S2 += __expf((x3.w - m) * rT);
  S2 = wred_sum(S2);

  if (lane == 0) {
    nll_out[row] = __logf(S2) - (xl - m) * rT;
  }
}

__global__ __launch_bounds__(256) void ats_mean_kernel(
    const float* __restrict__ nll, float* __restrict__ out, int B) {
  __shared__ double sdata[256];
  double acc = 0.0;
  for (int i = threadIdx.x; i < B; i += 256) acc += (double)nll[i];
  sdata[threadIdx.x] = acc;
  __syncthreads();
#pragma unroll
  for (int s = 128; s > 0; s >>= 1) {
    if ((int)threadIdx.x < s) sdata[threadIdx.x] += sdata[threadIdx.x + s];
    __syncthreads();
  }
  if (threadIdx.x == 0) out[0] = (float)(sdata[0] / (double)B);
}

extern "C" void kernel_launch(void* const* d_in, const int* in_sizes, int n_in,
                              void* d_out, int out_size, void* d_ws, size_t ws_size,
                              hipStream_t stream) {
  (void)n_in; (void)out_size; (void)ws_size;
  const float* X    = (const float*)d_in[0];
  const int*   lab  = (const int*)d_in[1];
  const float* wL   = (const float*)d_in[2];
  const float* wH   = (const float*)d_in[3];
  const float* bb   = (const float*)d_in[4];
  const int B = in_sizes[1];           // 65536 labels
  float* nll = (float*)d_ws;           // B floats = 256 KB scratch
  float* out = (float*)d_out;

  const int rows_per_block = kBlock / 64;
  const int grid = (B + rows_per_block - 1) / rows_per_block;
  ats_row_kernel<<<grid, kBlock, 0, stream>>>(X, lab, wL, wH, bb, nll, B);
  ats_mean_kernel<<<1, 256, 0, stream>>>(nll, out, B);
}

// Round 3
// 64.125 us; speedup vs baseline: 1.7737x; 1.7737x over previous
//
#include <hip/hip_runtime.h>
#include <float.h>
#include <math.h>

// B=65536 rows, C=1000 cols, fp32. One wave (64 lanes) per row, persistent
// grid-stride waves with next-row register prefetch (software pipeline).
// Per row (X read from HBM exactly once, row lives in 16 VGPRs/lane):
//   pass1: m = max(x), L = dot(x, wL)        (wL cached in 16 VGPRs per wave)
//   pass2: S = sum exp(x-m), W = sum exp(x-m)*x
//   H_hat = W/S - m - log S ;  T = clip(softplus(L + wH*H_hat/lnC + b), EPS)
//   pass3 (regs only): S2 = sum exp((x-m)/T); nll = log S2 - (x_lab - m)/T
// Mean fused: per-block double partial -> d_ws, tiny final kernel (2048 vals).

static constexpr int   kC4    = 250;   // float4 per row (1000 floats)
static constexpr int   kBlock = 256;   // 4 waves per block
static constexpr int   kGrid  = 2048;  // 8192 waves -> 8 rows/wave at B=65536
static constexpr int   kWavesTotal = kGrid * (kBlock / 64);
static constexpr float kEps   = 1.1920928955078125e-07f;  // FLT_EPSILON
static constexpr float kLogC  = 6.907755279f;             // ln(1000)

__device__ __forceinline__ float wred_max(float v) {
#pragma unroll
  for (int off = 32; off > 0; off >>= 1) v = fmaxf(v, __shfl_xor(v, off, 64));
  return v;
}
__device__ __forceinline__ float wred_sum(float v) {
#pragma unroll
  for (int off = 32; off > 0; off >>= 1) v += __shfl_xor(v, off, 64);
  return v;
}

__device__ __forceinline__ void p1_dot_max(const float4 c, const float4 w,
                                           float& L, float& m) {
  L = fmaf(c.x, w.x, L); L = fmaf(c.y, w.y, L);
  L = fmaf(c.z, w.z, L); L = fmaf(c.w, w.w, L);
  m = fmaxf(m, fmaxf(fmaxf(c.x, c.y), fmaxf(c.z, c.w)));
}
__device__ __forceinline__ void p2_sumexp(const float4 c, const float m,
                                          float& S, float& W) {
  float e;
  e = __expf(c.x - m); S += e; W = fmaf(e, c.x, W);
  e = __expf(c.y - m); S += e; W = fmaf(e, c.y, W);
  e = __expf(c.z - m); S += e; W = fmaf(e, c.z, W);
  e = __expf(c.w - m); S += e; W = fmaf(e, c.w, W);
}
__device__ __forceinline__ void p3_sumexp2(const float4 c, const float rT,
                                           const float nmrT, float& S2) {
  S2 += __expf(fmaf(c.x, rT, nmrT)); S2 += __expf(fmaf(c.y, rT, nmrT));
  S2 += __expf(fmaf(c.z, rT, nmrT)); S2 += __expf(fmaf(c.w, rT, nmrT));
}

#define SENT4 make_float4(-FLT_MAX, -FLT_MAX, -FLT_MAX, -FLT_MAX)

__global__ __launch_bounds__(kBlock) void ats_row_kernel(
    const float* __restrict__ X, const int* __restrict__ labels,
    const float* __restrict__ wL, const float* __restrict__ wH,
    const float* __restrict__ bb, double* __restrict__ partial, int B) {
  const int lane   = threadIdx.x & 63;
  const int wib    = threadIdx.x >> 6;                    // wave in block
  const int wid    = blockIdx.x * (kBlock / 64) + wib;    // global wave id
  const bool tailok = lane < (kC4 - 192);                 // lanes 0..57

  // wL cached once per wave (row-invariant), 16 VGPRs
  const float4* WLr = reinterpret_cast<const float4*>(wL);
  const float4 w0 = WLr[lane];
  const float4 w1 = WLr[64 + lane];
  const float4 w2 = WLr[128 + lane];
  const float4 w3 = tailok ? WLr[192 + lane] : make_float4(0.f, 0.f, 0.f, 0.f);
  const float wH0 = wH[0];
  const float b0  = bb[0];

  double acc = 0.0;

  int row = wid;
  float4 c0, c1, c2, c3;
  int labc = 0;
  if (row < B) {  // prefetch first row
    const float4* Xr = reinterpret_cast<const float4*>(X) + (size_t)row * kC4;
    c0 = Xr[lane]; c1 = Xr[64 + lane]; c2 = Xr[128 + lane];
    c3 = tailok ? Xr[192 + lane] : SENT4;
    labc = labels[row];
  }

  for (; row < B; row += kWavesTotal) {
    // ---- prefetch next row (issues before the compute below, hides HBM lat)
    const int nrow = row + kWavesTotal;
    float4 n0 = SENT4, n1 = SENT4, n2 = SENT4, n3 = SENT4;
    int labn = 0;
    if (nrow < B) {
      const float4* Xn = reinterpret_cast<const float4*>(X) + (size_t)nrow * kC4;
      n0 = Xn[lane]; n1 = Xn[64 + lane]; n2 = Xn[128 + lane];
      n3 = tailok ? Xn[192 + lane] : SENT4;
      labn = labels[nrow];
    }

    // ---- pass1: max + dot (sentinel -FLT_MAX never wins max; w3=0 on tail)
    float L = 0.f, m = -FLT_MAX;
    p1_dot_max(c0, w0, L, m); p1_dot_max(c1, w1, L, m);
    p1_dot_max(c2, w2, L, m); p1_dot_max(c3, w3, L, m);
    m = wred_max(m);

    // ---- pass2: S = sum e, W = sum e*x  (exp underflows to 0 on sentinel)
    float S = 0.f, W = 0.f;
    p2_sumexp(c0, m, S, W); p2_sumexp(c1, m, S, W);
    p2_sumexp(c2, m, S, W); p2_sumexp(c3, m, S, W);
    S = wred_sum(S);
    W = wred_sum(W);
    L = wred_sum(L);

    // ---- x[label]: slot/elem are wave-uniform, one shfl broadcast
    const int c4l = labc >> 2;
    const int sl  = c4l >> 6, ln = c4l & 63, el = labc & 3;
    float4 v = (sl == 0) ? c0 : (sl == 1) ? c1 : (sl == 2) ? c2 : c3;
    float cand = (el == 0) ? v.x : (el == 1) ? v.y : (el == 2) ? v.z : v.w;
    const float xl = __shfl(cand, ln, 64);

    // ---- temperature
    const float Hhat = W / S - m - __logf(S);
    const float a    = L + wH0 * (Hhat / kLogC) + b0;
    const float sp   = (a > 0.f) ? (a + log1pf(__expf(-a))) : log1pf(__expf(a));
    const float T    = fmaxf(sp, kEps);
    const float rT   = 1.0f / T;
    const float nmrT = -m * rT;

    // ---- pass3: S2 = sum exp((x-m)/T)  (registers only)
    float S2 = 0.f;
    p3_sumexp2(c0, rT, nmrT, S2); p3_sumexp2(c1, rT, nmrT, S2);
    p3_sumexp2(c2, rT, nmrT, S2); p3_sumexp2(c3, rT, nmrT, S2);
    S2 = wred_sum(S2);

    const float nll = __logf(S2) - fmaf(xl, rT, nmrT);  // logS2 - (xl-m)/T
    acc += (double)nll;

    // ---- rotate pipeline
    c0 = n0; c1 = n1; c2 = n2; c3 = n3; labc = labn;
  }

  // ---- block partial (all lanes hold identical acc; lane 0 per wave writes)
  __shared__ double sacc[kBlock / 64];
  if (lane == 0) sacc[wib] = acc;
  __syncthreads();
  if (threadIdx.x == 0)
    partial[blockIdx.x] = (sacc[0] + sacc[1]) + (sacc[2] + sacc[3]);
}

__global__ __launch_bounds__(256) void ats_final_kernel(
    const double* __restrict__ partial, float* __restrict__ out, int n, int B) {
  __shared__ double sdata[256];
  double a = 0.0;
  for (int i = threadIdx.x; i < n; i += 256) a += partial[i];
  sdata[threadIdx.x] = a;
  __syncthreads();
#pragma unroll
  for (int s = 128; s > 0; s >>= 1) {
    if ((int)threadIdx.x < s) sdata[threadIdx.x] += sdata[threadIdx.x + s];
    __syncthreads();
  }
  if (threadIdx.x == 0) out[0] = (float)(sdata[0] / (double)B);
}

extern "C" void kernel_launch(void* const* d_in, const int* in_sizes, int n_in,
                              void* d_out, int out_size, void* d_ws, size_t ws_size,
                              hipStream_t stream) {
  (void)n_in; (void)out_size; (void)ws_size;
  const float* X   = (const float*)d_in[0];
  const int*   lab = (const int*)d_in[1];
  const float* wL  = (const float*)d_in[2];
  const float* wH  = (const float*)d_in[3];
  const float* bb  = (const float*)d_in[4];
  const int B = in_sizes[1];            // 65536 labels
  double* partial = (double*)d_ws;      // kGrid doubles = 16 KB scratch
  float* out = (float*)d_out;

  ats_row_kernel<<<kGrid, kBlock, 0, stream>>>(X, lab, wL, wH, bb, partial, B);
  ats_final_kernel<<<1, 256, 0, stream>>>(partial, out, kGrid, B);
}